// Round 1
// baseline (309.834 us; speedup 1.0000x reference)
//
#include <hip/hip_runtime.h>
#include <hip/hip_bf16.h>

using bf16x8 = __attribute__((ext_vector_type(8))) short;
using f32x4  = __attribute__((ext_vector_type(4))) float;

#define SEQ      2048
#define DMODEL   1024
#define NHEADS   16
#define HDIM     64
#define MROWS    4096   // BATCH*SEQ

__device__ __forceinline__ unsigned short f2bf(float f) {
  union { float f; unsigned u; } c; c.f = f;
  unsigned r = c.u + 0x7FFFu + ((c.u >> 16) & 1u);
  return (unsigned short)(r >> 16);
}

__device__ __forceinline__ void gload16(const void* g, void* s) {
  __builtin_amdgcn_global_load_lds(
      (const __attribute__((address_space(1))) void*)g,
      (__attribute__((address_space(3))) void*)s, 16, 0, 0);
}

// ---------------- fp32 -> bf16 conversion (vectorized, 4/thread) -------------
__global__ void cvt_bf16(const float* __restrict__ in, unsigned short* __restrict__ out, int n4) {
  int i = blockIdx.x * blockDim.x + threadIdx.x;
  if (i >= n4) return;
  const float4 v = ((const float4*)in)[i];
  ushort4 o;
  o.x = f2bf(v.x); o.y = f2bf(v.y); o.z = f2bf(v.z); o.w = f2bf(v.w);
  ((ushort4*)out)[i] = o;
}

// ---------------- fused QKV projection GEMM ---------------------------------
// C[m][n] = sum_k A[m][k] * W[n][k]  (W row-major (out,in) == B^T layout)
// M=4096, N=3*1024 (Wq|Wk|Wv), K=1024. 128x128 tile, BK=64, 4 waves (2x2).
__global__ __launch_bounds__(256, 2)
void gemm_qkv(const unsigned short* __restrict__ Ab,
              const unsigned short* __restrict__ Wqb,
              const unsigned short* __restrict__ Wkb,
              const unsigned short* __restrict__ Wvb,
              const float* __restrict__ bq, const float* __restrict__ bk,
              const float* __restrict__ bv,
              unsigned short* __restrict__ Qo, unsigned short* __restrict__ Ko,
              unsigned short* __restrict__ Vto)
{
  __shared__ unsigned short As[128 * 64];
  __shared__ unsigned short Bs[128 * 64];
  const int t  = threadIdx.x;
  const int w  = t >> 6, l = t & 63;
  const int lr = l & 15, lg = l >> 4;
  const int bm = blockIdx.x / 24;   // 0..31
  const int bn = blockIdx.x % 24;   // 0..23
  const int which = bn >> 3;        // 0=Q 1=K 2=V
  const unsigned short* Bsrc = which == 0 ? Wqb : (which == 1 ? Wkb : Wvb);
  const float* biasp = which == 0 ? bq : (which == 1 ? bk : bv);
  const int bnw = bn & 7;
  const int wm = w >> 1, wn = w & 1;

  const char* Agp = (const char*)Ab + (size_t)bm * 128 * 2048;   // 2048 B per row (K=1024 bf16)
  const char* Bgp = (const char*)Bsrc + (size_t)bnw * 128 * 2048;

  f32x4 acc[4][4];
  #pragma unroll
  for (int a = 0; a < 4; ++a)
    #pragma unroll
    for (int b = 0; b < 4; ++b) acc[a][b] = (f32x4){0.f, 0.f, 0.f, 0.f};

  for (int kt = 0; kt < 16; ++kt) {
    const int kbyte = kt * 128;
    #pragma unroll
    for (int i = 0; i < 4; ++i) {
      int idx  = i * 256 + t;
      int row  = idx >> 3;
      int colb = (idx & 7) << 4;
      gload16(Agp + (size_t)row * 2048 + kbyte + colb, (char*)As + idx * 16);
      gload16(Bgp + (size_t)row * 2048 + kbyte + colb, (char*)Bs + idx * 16);
    }
    __syncthreads();
    #pragma unroll
    for (int kk = 0; kk < 2; ++kk) {
      bf16x8 af[4], bfr[4];
      #pragma unroll
      for (int x = 0; x < 4; ++x) {
        af[x]  = *(const bf16x8*)&As[(wm * 64 + x * 16 + lr) * 64 + kk * 32 + lg * 8];
        bfr[x] = *(const bf16x8*)&Bs[(wn * 64 + x * 16 + lr) * 64 + kk * 32 + lg * 8];
      }
      #pragma unroll
      for (int xa = 0; xa < 4; ++xa)
        #pragma unroll
        for (int xb = 0; xb < 4; ++xb)
          acc[xa][xb] = __builtin_amdgcn_mfma_f32_16x16x32_bf16(af[xa], bfr[xb], acc[xa][xb], 0, 0, 0);
    }
    __syncthreads();
  }

  // Epilogue: write Q/K as [(b*16+h)*2048+s][dh], V transposed [(b*16+h)*64+dh][s]
  #pragma unroll
  for (int xb = 0; xb < 4; ++xb) {
    int colg = bnw * 128 + wn * 64 + xb * 16 + lr;   // 0..1023 within this weight
    int h  = colg >> 6, dh = colg & 63;
    float biasv = biasp[colg];
    #pragma unroll
    for (int xa = 0; xa < 4; ++xa) {
      int row0 = bm * 128 + wm * 64 + xa * 16 + lg * 4;
      #pragma unroll
      for (int i = 0; i < 4; ++i) {
        int m = row0 + i;
        int b = m >> 11, s = m & 2047;
        unsigned short u = f2bf(acc[xa][xb][i] + biasv);
        if (which == 0)
          Qo[(((size_t)(b * NHEADS + h)) * SEQ + s) * HDIM + dh] = u;
        else if (which == 1)
          Ko[(((size_t)(b * NHEADS + h)) * SEQ + s) * HDIM + dh] = u;
        else
          Vto[(((size_t)(b * NHEADS + h)) * HDIM + dh) * SEQ + s] = u;
      }
    }
  }
}

// ---------------- causal flash attention ------------------------------------
// grid = 32 bh * 32 qblocks; 4 waves/block, each wave owns 16 q-rows.
__global__ __launch_bounds__(256, 2)
void attn_fwd(const unsigned short* __restrict__ Q,
              const unsigned short* __restrict__ K,
              const unsigned short* __restrict__ Vt,
              unsigned short* __restrict__ O)
{
  const int t = threadIdx.x;
  const int w = t >> 6, l = t & 63;
  const int lr = l & 15, lg = l >> 4;
  const int bh   = blockIdx.x >> 5;
  const int qblk = blockIdx.x & 31;
  const int b = bh >> 4, h = bh & 15;
  const int q0 = qblk * 64 + w * 16;

  const unsigned short* Qp = Q  + (size_t)bh * SEQ * HDIM;
  const unsigned short* Kp = K  + (size_t)bh * SEQ * HDIM;
  const unsigned short* Vp = Vt + (size_t)bh * HDIM * SEQ;

  __shared__ unsigned short Plds[4][16][72];   // per-wave P tile, pad->2-way (free)

  bf16x8 qf[2];
  #pragma unroll
  for (int kk = 0; kk < 2; ++kk)
    qf[kk] = *(const bf16x8*)(Qp + (size_t)(q0 + lr) * HDIM + kk * 32 + lg * 8);

  f32x4 o[4];
  #pragma unroll
  for (int n = 0; n < 4; ++n) o[n] = (f32x4){0.f, 0.f, 0.f, 0.f};
  float mrow[4], lrow[4];
  #pragma unroll
  for (int i = 0; i < 4; ++i) { mrow[i] = -3.0e38f; lrow[i] = 0.f; }

  const int nkb = qblk + 1;
  for (int kb = 0; kb < nkb; ++kb) {
    const int kbase = kb * 64;
    // ---- S = Q K^T * scale
    f32x4 s[4];
    #pragma unroll
    for (int n = 0; n < 4; ++n) {
      f32x4 acc = (f32x4){0.f, 0.f, 0.f, 0.f};
      #pragma unroll
      for (int kk = 0; kk < 2; ++kk) {
        bf16x8 kf = *(const bf16x8*)(Kp + (size_t)(kbase + n * 16 + lr) * HDIM + kk * 32 + lg * 8);
        acc = __builtin_amdgcn_mfma_f32_16x16x32_bf16(qf[kk], kf, acc, 0, 0, 0);
      }
      #pragma unroll
      for (int i = 0; i < 4; ++i) s[n][i] = acc[i] * 0.125f;
    }
    // ---- causal mask on diagonal superblock
    if (kb == qblk) {
      #pragma unroll
      for (int n = 0; n < 4; ++n) {
        int key = kbase + n * 16 + lr;
        #pragma unroll
        for (int i = 0; i < 4; ++i) {
          int query = q0 + lg * 4 + i;
          if (key > query) s[n][i] = -3.0e38f;
        }
      }
    }
    // ---- online softmax (rows lg*4+i live across the 16 lanes of group lg)
    float tmax[4];
    #pragma unroll
    for (int i = 0; i < 4; ++i)
      tmax[i] = fmaxf(fmaxf(s[0][i], s[1][i]), fmaxf(s[2][i], s[3][i]));
    #pragma unroll
    for (int mk = 1; mk < 16; mk <<= 1)
      #pragma unroll
      for (int i = 0; i < 4; ++i)
        tmax[i] = fmaxf(tmax[i], __shfl_xor(tmax[i], mk, 16));
    float cs[4];
    #pragma unroll
    for (int i = 0; i < 4; ++i) {
      float mn = fmaxf(mrow[i], tmax[i]);
      cs[i] = __expf(mrow[i] - mn);
      mrow[i] = mn;
    }
    float psum[4] = {0.f, 0.f, 0.f, 0.f};
    #pragma unroll
    for (int n = 0; n < 4; ++n) {
      #pragma unroll
      for (int i = 0; i < 4; ++i) {
        float p = __expf(s[n][i] - mrow[i]);
        psum[i] += p;
        Plds[w][lg * 4 + i][n * 16 + lr] = f2bf(p);
      }
    }
    #pragma unroll
    for (int mk = 1; mk < 16; mk <<= 1)
      #pragma unroll
      for (int i = 0; i < 4; ++i)
        psum[i] += __shfl_xor(psum[i], mk, 16);
    #pragma unroll
    for (int i = 0; i < 4; ++i) lrow[i] = lrow[i] * cs[i] + psum[i];
    #pragma unroll
    for (int n = 0; n < 4; ++n)
      #pragma unroll
      for (int i = 0; i < 4; ++i) o[n][i] *= cs[i];
    // ---- O += P @ V  (A-frag of P via LDS transpose; B-frag from Vt rows)
    #pragma unroll
    for (int kk = 0; kk < 2; ++kk) {
      bf16x8 af = *(const bf16x8*)&Plds[w][lr][kk * 32 + lg * 8];
      #pragma unroll
      for (int n = 0; n < 4; ++n) {
        bf16x8 vf = *(const bf16x8*)(Vp + (size_t)(n * 16 + lr) * SEQ + kbase + kk * 32 + lg * 8);
        o[n] = __builtin_amdgcn_mfma_f32_16x16x32_bf16(af, vf, o[n], 0, 0, 0);
      }
    }
  }
  // ---- epilogue: attn[(b*S+s)][h*64+dh] bf16
  #pragma unroll
  for (int n = 0; n < 4; ++n) {
    int col = h * HDIM + n * 16 + lr;
    #pragma unroll
    for (int i = 0; i < 4; ++i) {
      int srow = q0 + lg * 4 + i;
      float v = o[n][i] / lrow[i];
      O[((size_t)(b * SEQ + srow)) * DMODEL + col] = f2bf(v);
    }
  }
}

// ---------------- output projection GEMM (fp32 out + bias) ------------------
__global__ __launch_bounds__(256, 2)
void gemm_out(const unsigned short* __restrict__ Ab, const unsigned short* __restrict__ Bb,
              const float* __restrict__ bias, float* __restrict__ C)
{
  __shared__ unsigned short As[128 * 64];
  __shared__ unsigned short Bs[128 * 64];
  const int t  = threadIdx.x;
  const int w  = t >> 6, l = t & 63;
  const int lr = l & 15, lg = l >> 4;
  const int bm = blockIdx.x >> 3;
  const int bn = blockIdx.x & 7;
  const int wm = w >> 1, wn = w & 1;

  const char* Agp = (const char*)Ab + (size_t)bm * 128 * 2048;
  const char* Bgp = (const char*)Bb + (size_t)bn * 128 * 2048;

  f32x4 acc[4][4];
  #pragma unroll
  for (int a = 0; a < 4; ++a)
    #pragma unroll
    for (int b = 0; b < 4; ++b) acc[a][b] = (f32x4){0.f, 0.f, 0.f, 0.f};

  for (int kt = 0; kt < 16; ++kt) {
    const int kbyte = kt * 128;
    #pragma unroll
    for (int i = 0; i < 4; ++i) {
      int idx  = i * 256 + t;
      int row  = idx >> 3;
      int colb = (idx & 7) << 4;
      gload16(Agp + (size_t)row * 2048 + kbyte + colb, (char*)As + idx * 16);
      gload16(Bgp + (size_t)row * 2048 + kbyte + colb, (char*)Bs + idx * 16);
    }
    __syncthreads();
    #pragma unroll
    for (int kk = 0; kk < 2; ++kk) {
      bf16x8 af[4], bfr[4];
      #pragma unroll
      for (int x = 0; x < 4; ++x) {
        af[x]  = *(const bf16x8*)&As[(wm * 64 + x * 16 + lr) * 64 + kk * 32 + lg * 8];
        bfr[x] = *(const bf16x8*)&Bs[(wn * 64 + x * 16 + lr) * 64 + kk * 32 + lg * 8];
      }
      #pragma unroll
      for (int xa = 0; xa < 4; ++xa)
        #pragma unroll
        for (int xb = 0; xb < 4; ++xb)
          acc[xa][xb] = __builtin_amdgcn_mfma_f32_16x16x32_bf16(af[xa], bfr[xb], acc[xa][xb], 0, 0, 0);
    }
    __syncthreads();
  }
  #pragma unroll
  for (int xb = 0; xb < 4; ++xb) {
    int col = bn * 128 + wn * 64 + xb * 16 + lr;
    float bvv = bias[col];
    #pragma unroll
    for (int xa = 0; xa < 4; ++xa) {
      int row0 = bm * 128 + wm * 64 + xa * 16 + lg * 4;
      #pragma unroll
      for (int i = 0; i < 4; ++i)
        C[(size_t)(row0 + i) * DMODEL + col] = acc[xa][xb][i] + bvv;
    }
  }
}

// ---------------- launcher ---------------------------------------------------
extern "C" void kernel_launch(void* const* d_in, const int* in_sizes, int n_in,
                              void* d_out, int out_size, void* d_ws, size_t ws_size,
                              hipStream_t stream)
{
  const float* x  = (const float*)d_in[0];
  // d_in[1] is the causal mask — constant tril, applied analytically in attn_fwd.
  const float* Wq = (const float*)d_in[2];
  const float* bq = (const float*)d_in[3];
  const float* Wk = (const float*)d_in[4];
  const float* bk = (const float*)d_in[5];
  const float* Wv = (const float*)d_in[6];
  const float* bv = (const float*)d_in[7];
  const float* Wo = (const float*)d_in[8];
  const float* bo = (const float*)d_in[9];

  char* ws = (char*)d_ws;
  const size_t MB = 1024 * 1024;
  unsigned short* xb   = (unsigned short*)(ws + 0);        // 8 MB  [4096][1024]
  unsigned short* Wqb  = (unsigned short*)(ws + 8  * MB);  // 2 MB
  unsigned short* Wkb  = (unsigned short*)(ws + 10 * MB);  // 2 MB
  unsigned short* Wvb  = (unsigned short*)(ws + 12 * MB);  // 2 MB
  unsigned short* Wob  = (unsigned short*)(ws + 14 * MB);  // 2 MB
  unsigned short* Qb   = (unsigned short*)(ws + 16 * MB);  // 8 MB  [(bh)*S+s][dh]
  unsigned short* Kb   = (unsigned short*)(ws + 24 * MB);  // 8 MB  [(bh)*S+s][dh]
  unsigned short* Vtb  = (unsigned short*)(ws + 32 * MB);  // 8 MB  [(bh)*64+dh][s]
  unsigned short* Attn = (unsigned short*)(ws + 40 * MB);  // 8 MB  [b*S+s][dmodel]

  cvt_bf16<<<4096, 256, 0, stream>>>(x,  xb,  1048576);
  cvt_bf16<<<1024, 256, 0, stream>>>(Wq, Wqb, 262144);
  cvt_bf16<<<1024, 256, 0, stream>>>(Wk, Wkb, 262144);
  cvt_bf16<<<1024, 256, 0, stream>>>(Wv, Wvb, 262144);
  cvt_bf16<<<1024, 256, 0, stream>>>(Wo, Wob, 262144);
  gemm_qkv<<<768, 256, 0, stream>>>(xb, Wqb, Wkb, Wvb, bq, bk, bv, Qb, Kb, Vtb);
  attn_fwd<<<1024, 256, 0, stream>>>(Qb, Kb, Vtb, Attn);
  gemm_out<<<256, 256, 0, stream>>>(Attn, Wob, bo, (float*)d_out);
}

// Round 2
// 246.250 us; speedup vs baseline: 1.2582x; 1.2582x over previous
//
#include <hip/hip_runtime.h>
#include <hip/hip_bf16.h>

using bf16x8 = __attribute__((ext_vector_type(8))) short;
using f32x4  = __attribute__((ext_vector_type(4))) float;

#define SEQ      2048
#define DMODEL   1024
#define NHEADS   16
#define HDIM     64
#define MROWS    4096   // BATCH*SEQ

__device__ __forceinline__ unsigned short f2bf(float f) {
  union { float f; unsigned u; } c; c.f = f;
  unsigned r = c.u + 0x7FFFu + ((c.u >> 16) & 1u);
  return (unsigned short)(r >> 16);
}

__device__ __forceinline__ void gload16(const void* g, void* s) {
  __builtin_amdgcn_global_load_lds(
      (const __attribute__((address_space(1))) void*)g,
      (__attribute__((address_space(3))) void*)s, 16, 0, 0);
}

// ---------------- fp32 -> bf16 conversion (vectorized, 4/thread) -------------
__global__ void cvt_bf16(const float* __restrict__ in, unsigned short* __restrict__ out, int n4) {
  int i = blockIdx.x * blockDim.x + threadIdx.x;
  if (i >= n4) return;
  const float4 v = ((const float4*)in)[i];
  ushort4 o;
  o.x = f2bf(v.x); o.y = f2bf(v.y); o.z = f2bf(v.z); o.w = f2bf(v.w);
  ((ushort4*)out)[i] = o;
}

// ---------------- fused QKV projection GEMM ---------------------------------
__global__ __launch_bounds__(256, 2)
void gemm_qkv(const unsigned short* __restrict__ Ab,
              const unsigned short* __restrict__ Wqb,
              const unsigned short* __restrict__ Wkb,
              const unsigned short* __restrict__ Wvb,
              const float* __restrict__ bq, const float* __restrict__ bk,
              const float* __restrict__ bv,
              unsigned short* __restrict__ Qo, unsigned short* __restrict__ Ko,
              unsigned short* __restrict__ Vto)
{
  __shared__ unsigned short As[128 * 64];
  __shared__ unsigned short Bs[128 * 64];
  const int t  = threadIdx.x;
  const int w  = t >> 6, l = t & 63;
  const int lr = l & 15, lg = l >> 4;
  const int bm = blockIdx.x / 24;   // 0..31
  const int bn = blockIdx.x % 24;   // 0..23
  const int which = bn >> 3;        // 0=Q 1=K 2=V
  const unsigned short* Bsrc = which == 0 ? Wqb : (which == 1 ? Wkb : Wvb);
  const float* biasp = which == 0 ? bq : (which == 1 ? bk : bv);
  const int bnw = bn & 7;
  const int wm = w >> 1, wn = w & 1;

  const char* Agp = (const char*)Ab + (size_t)bm * 128 * 2048;
  const char* Bgp = (const char*)Bsrc + (size_t)bnw * 128 * 2048;

  f32x4 acc[4][4];
  #pragma unroll
  for (int a = 0; a < 4; ++a)
    #pragma unroll
    for (int b = 0; b < 4; ++b) acc[a][b] = (f32x4){0.f, 0.f, 0.f, 0.f};

  for (int kt = 0; kt < 16; ++kt) {
    const int kbyte = kt * 128;
    #pragma unroll
    for (int i = 0; i < 4; ++i) {
      int idx  = i * 256 + t;
      int row  = idx >> 3;
      int colb = (idx & 7) << 4;
      gload16(Agp + (size_t)row * 2048 + kbyte + colb, (char*)As + idx * 16);
      gload16(Bgp + (size_t)row * 2048 + kbyte + colb, (char*)Bs + idx * 16);
    }
    __syncthreads();
    #pragma unroll
    for (int kk = 0; kk < 2; ++kk) {
      bf16x8 af[4], bfr[4];
      #pragma unroll
      for (int x = 0; x < 4; ++x) {
        af[x]  = *(const bf16x8*)&As[(wm * 64 + x * 16 + lr) * 64 + kk * 32 + lg * 8];
        bfr[x] = *(const bf16x8*)&Bs[(wn * 64 + x * 16 + lr) * 64 + kk * 32 + lg * 8];
      }
      #pragma unroll
      for (int xa = 0; xa < 4; ++xa)
        #pragma unroll
        for (int xb = 0; xb < 4; ++xb)
          acc[xa][xb] = __builtin_amdgcn_mfma_f32_16x16x32_bf16(af[xa], bfr[xb], acc[xa][xb], 0, 0, 0);
    }
    __syncthreads();
  }

  #pragma unroll
  for (int xb = 0; xb < 4; ++xb) {
    int colg = bnw * 128 + wn * 64 + xb * 16 + lr;
    int h  = colg >> 6, dh = colg & 63;
    float biasv = biasp[colg];
    #pragma unroll
    for (int xa = 0; xa < 4; ++xa) {
      int row0 = bm * 128 + wm * 64 + xa * 16 + lg * 4;
      #pragma unroll
      for (int i = 0; i < 4; ++i) {
        int m = row0 + i;
        int b = m >> 11, s = m & 2047;
        unsigned short u = f2bf(acc[xa][xb][i] + biasv);
        if (which == 0)
          Qo[(((size_t)(b * NHEADS + h)) * SEQ + s) * HDIM + dh] = u;
        else if (which == 1)
          Ko[(((size_t)(b * NHEADS + h)) * SEQ + s) * HDIM + dh] = u;
        else
          Vto[(((size_t)(b * NHEADS + h)) * HDIM + dh) * SEQ + s] = u;
      }
    }
  }
}

// ---------------- causal flash attention (balanced, 8 waves, 32 rows/wave) ---
// grid = 32 bh * 8 pair-blocks; waves 0-3 -> q-super pr, waves 4-7 -> 15-pr.
// Each wave owns 32 q-rows (2 MFMA row-frags); per-wave causal trip count.
__global__ __launch_bounds__(512, 2)
void attn_fwd(const unsigned short* __restrict__ Q,
              const unsigned short* __restrict__ K,
              const unsigned short* __restrict__ Vt,
              unsigned short* __restrict__ O)
{
  const int t = threadIdx.x;
  const int w = t >> 6, l = t & 63;
  const int lr = l & 15, lg = l >> 4;
  const int bh = blockIdx.x >> 3;
  const int pr = blockIdx.x & 7;
  const int b = bh >> 4, h = bh & 15;
  const int half = w >> 2, wl = w & 3;
  const int qsuper = half == 0 ? pr : 15 - pr;
  const int q0 = qsuper * 128 + wl * 32;

  const unsigned short* Qp = Q  + (size_t)bh * SEQ * HDIM;
  const unsigned short* Kp = K  + (size_t)bh * SEQ * HDIM;
  const unsigned short* Vp = Vt + (size_t)bh * HDIM * SEQ;

  __shared__ unsigned short Plds[8][2][16][72];   // per-wave P tiles

  bf16x8 qf[2][2];
  #pragma unroll
  for (int f = 0; f < 2; ++f)
    #pragma unroll
    for (int kk = 0; kk < 2; ++kk)
      qf[f][kk] = *(const bf16x8*)(Qp + (size_t)(q0 + f * 16 + lr) * HDIM + kk * 32 + lg * 8);

  f32x4 o[2][4];
  #pragma unroll
  for (int f = 0; f < 2; ++f)
    #pragma unroll
    for (int n = 0; n < 4; ++n) o[f][n] = (f32x4){0.f, 0.f, 0.f, 0.f};
  float mrow[2][4], lrow[2][4];
  #pragma unroll
  for (int f = 0; f < 2; ++f)
    #pragma unroll
    for (int i = 0; i < 4; ++i) { mrow[f][i] = -3.0e38f; lrow[f][i] = 0.f; }

  const int nkb = (q0 >> 6) + 1;
  for (int kb = 0; kb < nkb; ++kb) {
    const int kbase = kb * 64;
    // ---- K fragments (shared by both row-frags)
    bf16x8 kf[4][2];
    #pragma unroll
    for (int n = 0; n < 4; ++n)
      #pragma unroll
      for (int kk = 0; kk < 2; ++kk)
        kf[n][kk] = *(const bf16x8*)(Kp + (size_t)(kbase + n * 16 + lr) * HDIM + kk * 32 + lg * 8);
    // ---- S = Q K^T (unscaled; scale folded into exp)
    f32x4 s[2][4];
    #pragma unroll
    for (int f = 0; f < 2; ++f)
      #pragma unroll
      for (int n = 0; n < 4; ++n) {
        f32x4 acc = (f32x4){0.f, 0.f, 0.f, 0.f};
        #pragma unroll
        for (int kk = 0; kk < 2; ++kk)
          acc = __builtin_amdgcn_mfma_f32_16x16x32_bf16(qf[f][kk], kf[n][kk], acc, 0, 0, 0);
        s[f][n] = acc;
      }
    // ---- causal mask only on the final (diagonal-touching) block
    if (kb == nkb - 1) {
      #pragma unroll
      for (int f = 0; f < 2; ++f)
        #pragma unroll
        for (int n = 0; n < 4; ++n) {
          int key = kbase + n * 16 + lr;
          #pragma unroll
          for (int i = 0; i < 4; ++i) {
            int query = q0 + f * 16 + lg * 4 + i;
            if (key > query) s[f][n][i] = -3.0e38f;
          }
        }
    }
    // ---- online softmax, both frags interleaved for ILP
    float tmax[2][4];
    #pragma unroll
    for (int f = 0; f < 2; ++f)
      #pragma unroll
      for (int i = 0; i < 4; ++i)
        tmax[f][i] = fmaxf(fmaxf(s[f][0][i], s[f][1][i]), fmaxf(s[f][2][i], s[f][3][i]));
    #pragma unroll
    for (int mk = 1; mk < 16; mk <<= 1)
      #pragma unroll
      for (int f = 0; f < 2; ++f)
        #pragma unroll
        for (int i = 0; i < 4; ++i)
          tmax[f][i] = fmaxf(tmax[f][i], __shfl_xor(tmax[f][i], mk, 16));
    float cs[2][4];
    #pragma unroll
    for (int f = 0; f < 2; ++f)
      #pragma unroll
      for (int i = 0; i < 4; ++i) {
        float mn = fmaxf(mrow[f][i], tmax[f][i]);
        cs[f][i] = __expf((mrow[f][i] - mn) * 0.125f);
        mrow[f][i] = mn;
      }
    float psum[2][4] = {{0.f,0.f,0.f,0.f},{0.f,0.f,0.f,0.f}};
    #pragma unroll
    for (int f = 0; f < 2; ++f)
      #pragma unroll
      for (int n = 0; n < 4; ++n)
        #pragma unroll
        for (int i = 0; i < 4; ++i) {
          float p = __expf((s[f][n][i] - mrow[f][i]) * 0.125f);
          psum[f][i] += p;
          Plds[w][f][lg * 4 + i][n * 16 + lr] = f2bf(p);
        }
    #pragma unroll
    for (int mk = 1; mk < 16; mk <<= 1)
      #pragma unroll
      for (int f = 0; f < 2; ++f)
        #pragma unroll
        for (int i = 0; i < 4; ++i)
          psum[f][i] += __shfl_xor(psum[f][i], mk, 16);
    #pragma unroll
    for (int f = 0; f < 2; ++f)
      #pragma unroll
      for (int i = 0; i < 4; ++i) lrow[f][i] = lrow[f][i] * cs[f][i] + psum[f][i];
    #pragma unroll
    for (int f = 0; f < 2; ++f)
      #pragma unroll
      for (int n = 0; n < 4; ++n)
        #pragma unroll
        for (int i = 0; i < 4; ++i) o[f][n][i] *= cs[f][i];
    // ---- O += P @ V   (V fragments shared by both row-frags)
    #pragma unroll
    for (int kk = 0; kk < 2; ++kk) {
      bf16x8 af0 = *(const bf16x8*)&Plds[w][0][lr][kk * 32 + lg * 8];
      bf16x8 af1 = *(const bf16x8*)&Plds[w][1][lr][kk * 32 + lg * 8];
      #pragma unroll
      for (int n = 0; n < 4; ++n) {
        bf16x8 vf = *(const bf16x8*)(Vp + (size_t)(n * 16 + lr) * SEQ + kbase + kk * 32 + lg * 8);
        o[0][n] = __builtin_amdgcn_mfma_f32_16x16x32_bf16(af0, vf, o[0][n], 0, 0, 0);
        o[1][n] = __builtin_amdgcn_mfma_f32_16x16x32_bf16(af1, vf, o[1][n], 0, 0, 0);
      }
    }
  }
  // ---- epilogue
  #pragma unroll
  for (int f = 0; f < 2; ++f)
    #pragma unroll
    for (int n = 0; n < 4; ++n) {
      int col = h * HDIM + n * 16 + lr;
      #pragma unroll
      for (int i = 0; i < 4; ++i) {
        int srow = q0 + f * 16 + lg * 4 + i;
        float v = o[f][n][i] / lrow[f][i];
        O[((size_t)(b * SEQ + srow)) * DMODEL + col] = f2bf(v);
      }
    }
}

// ---------------- output projection GEMM (fp32 out + bias) ------------------
__global__ __launch_bounds__(256, 2)
void gemm_out(const unsigned short* __restrict__ Ab, const unsigned short* __restrict__ Bb,
              const float* __restrict__ bias, float* __restrict__ C)
{
  __shared__ unsigned short As[128 * 64];
  __shared__ unsigned short Bs[128 * 64];
  const int t  = threadIdx.x;
  const int w  = t >> 6, l = t & 63;
  const int lr = l & 15, lg = l >> 4;
  const int bm = blockIdx.x >> 3;
  const int bn = blockIdx.x & 7;
  const int wm = w >> 1, wn = w & 1;

  const char* Agp = (const char*)Ab + (size_t)bm * 128 * 2048;
  const char* Bgp = (const char*)Bb + (size_t)bn * 128 * 2048;

  f32x4 acc[4][4];
  #pragma unroll
  for (int a = 0; a < 4; ++a)
    #pragma unroll
    for (int b = 0; b < 4; ++b) acc[a][b] = (f32x4){0.f, 0.f, 0.f, 0.f};

  for (int kt = 0; kt < 16; ++kt) {
    const int kbyte = kt * 128;
    #pragma unroll
    for (int i = 0; i < 4; ++i) {
      int idx  = i * 256 + t;
      int row  = idx >> 3;
      int colb = (idx & 7) << 4;
      gload16(Agp + (size_t)row * 2048 + kbyte + colb, (char*)As + idx * 16);
      gload16(Bgp + (size_t)row * 2048 + kbyte + colb, (char*)Bs + idx * 16);
    }
    __syncthreads();
    #pragma unroll
    for (int kk = 0; kk < 2; ++kk) {
      bf16x8 af[4], bfr[4];
      #pragma unroll
      for (int x = 0; x < 4; ++x) {
        af[x]  = *(const bf16x8*)&As[(wm * 64 + x * 16 + lr) * 64 + kk * 32 + lg * 8];
        bfr[x] = *(const bf16x8*)&Bs[(wn * 64 + x * 16 + lr) * 64 + kk * 32 + lg * 8];
      }
      #pragma unroll
      for (int xa = 0; xa < 4; ++xa)
        #pragma unroll
        for (int xb = 0; xb < 4; ++xb)
          acc[xa][xb] = __builtin_amdgcn_mfma_f32_16x16x32_bf16(af[xa], bfr[xb], acc[xa][xb], 0, 0, 0);
    }
    __syncthreads();
  }
  #pragma unroll
  for (int xb = 0; xb < 4; ++xb) {
    int col = bn * 128 + wn * 64 + xb * 16 + lr;
    float bvv = bias[col];
    #pragma unroll
    for (int xa = 0; xa < 4; ++xa) {
      int row0 = bm * 128 + wm * 64 + xa * 16 + lg * 4;
      #pragma unroll
      for (int i = 0; i < 4; ++i)
        C[(size_t)(row0 + i) * DMODEL + col] = acc[xa][xb][i] + bvv;
    }
  }
}

// ---------------- launcher ---------------------------------------------------
extern "C" void kernel_launch(void* const* d_in, const int* in_sizes, int n_in,
                              void* d_out, int out_size, void* d_ws, size_t ws_size,
                              hipStream_t stream)
{
  const float* x  = (const float*)d_in[0];
  // d_in[1] is the causal mask — constant tril, applied analytically in attn_fwd.
  const float* Wq = (const float*)d_in[2];
  const float* bq = (const float*)d_in[3];
  const float* Wk = (const float*)d_in[4];
  const float* bk = (const float*)d_in[5];
  const float* Wv = (const float*)d_in[6];
  const float* bv = (const float*)d_in[7];
  const float* Wo = (const float*)d_in[8];
  const float* bo = (const float*)d_in[9];

  char* ws = (char*)d_ws;
  const size_t MB = 1024 * 1024;
  unsigned short* xb   = (unsigned short*)(ws + 0);        // 8 MB  [4096][1024]
  unsigned short* Wqb  = (unsigned short*)(ws + 8  * MB);  // 2 MB
  unsigned short* Wkb  = (unsigned short*)(ws + 10 * MB);  // 2 MB
  unsigned short* Wvb  = (unsigned short*)(ws + 12 * MB);  // 2 MB
  unsigned short* Wob  = (unsigned short*)(ws + 14 * MB);  // 2 MB
  unsigned short* Qb   = (unsigned short*)(ws + 16 * MB);  // 8 MB  [(bh)*S+s][dh]
  unsigned short* Kb   = (unsigned short*)(ws + 24 * MB);  // 8 MB  [(bh)*S+s][dh]
  unsigned short* Vtb  = (unsigned short*)(ws + 32 * MB);  // 8 MB  [(bh)*64+dh][s]
  unsigned short* Attn = (unsigned short*)(ws + 40 * MB);  // 8 MB  [b*S+s][dmodel]

  cvt_bf16<<<4096, 256, 0, stream>>>(x,  xb,  1048576);
  cvt_bf16<<<1024, 256, 0, stream>>>(Wq, Wqb, 262144);
  cvt_bf16<<<1024, 256, 0, stream>>>(Wk, Wkb, 262144);
  cvt_bf16<<<1024, 256, 0, stream>>>(Wv, Wvb, 262144);
  cvt_bf16<<<1024, 256, 0, stream>>>(Wo, Wob, 262144);
  gemm_qkv<<<768, 256, 0, stream>>>(xb, Wqb, Wkb, Wvb, bq, bk, bv, Qb, Kb, Vtb);
  attn_fwd<<<256, 512, 0, stream>>>(Qb, Kb, Vtb, Attn);
  gemm_out<<<256, 256, 0, stream>>>(Attn, Wob, bo, (float*)d_out);
}